// Round 1
// baseline (1044.355 us; speedup 1.0000x reference)
//
#include <hip/hip_runtime.h>
#include <stdint.h>

#define B_    8
#define DK_   128
#define DV_   512
#define M_    3136      // H*W
#define N_    6272      // T*H*W
#define MT_   64
#define NT_   64
#define NSEG_ 8
#define MTILES_ 49      // 3136/64 exact
#define CAP_  262144
#define TH_   30.0f

// ---- monotone float<->uint key for atomicMax on floats ----
__device__ __forceinline__ unsigned fkey(float x) {
  unsigned u = __float_as_uint(x);
  return (u & 0x80000000u) ? ~u : (u | 0x80000000u);
}
__device__ __forceinline__ float fdec(unsigned k) {
  return __uint_as_float((k & 0x80000000u) ? (k & 0x7fffffffu) : ~k);
}

// ---- per-batch deterministic compaction of qmask/mmask ----
__global__ __launch_bounds__(256)
void scan_masks(const int* __restrict__ qmask, const int* __restrict__ mmask,
                int* __restrict__ qlist, int* __restrict__ nlist,
                int* __restrict__ qcnt, int* __restrict__ ncnt) {
  int b = blockIdx.x;
  int tid = threadIdx.x, lane = tid & 63, wv = tid >> 6;
  __shared__ int wsum[4];
  __shared__ int cbase;
  if (tid == 0) cbase = 0;
  __syncthreads();
  for (int base = 0; base < M_; base += 256) {
    int i = base + tid;
    int flag = (i < M_) ? (qmask[b * M_ + i] != 0) : 0;
    unsigned long long bal = __ballot(flag);
    int prefix = __popcll(bal & ((1ull << lane) - 1ull));
    if (lane == 0) wsum[wv] = __popcll(bal);
    __syncthreads();
    int woff = 0;
    for (int t = 0; t < wv; ++t) woff += wsum[t];
    int total = wsum[0] + wsum[1] + wsum[2] + wsum[3];
    if (flag) qlist[b * M_ + cbase + woff + prefix] = i;
    __syncthreads();
    if (tid == 0) cbase += total;
    __syncthreads();
  }
  if (tid == 0) { qcnt[b] = cbase; cbase = 0; }
  __syncthreads();
  for (int base = 0; base < N_; base += 256) {
    int i = base + tid;
    int flag = (i < N_) ? (mmask[b * N_ + i] != 0) : 0;
    unsigned long long bal = __ballot(flag);
    int prefix = __popcll(bal & ((1ull << lane) - 1ull));
    if (lane == 0) wsum[wv] = __popcll(bal);
    __syncthreads();
    int woff = 0;
    for (int t = 0; t < wv; ++t) woff += wsum[t];
    int total = wsum[0] + wsum[1] + wsum[2] + wsum[3];
    if (flag) nlist[b * N_ + cbase + woff + prefix] = i;
    __syncthreads();
    if (tid == 0) cbase += total;
    __syncthreads();
  }
  if (tid == 0) ncnt[b] = cbase;
}

// ---- tiled fp32 score GEMM; PHASE 1 = column max, PHASE 2 = exp + entry append ----
template <int PHASE>
__global__ __launch_bounds__(256)
void score_kernel(const float* __restrict__ qkey, const float* __restrict__ mkey,
                  const int* __restrict__ qlist, const int* __restrict__ nlist,
                  const int* __restrict__ qcnt, const int* __restrict__ ncnt,
                  unsigned* __restrict__ maxkey, float* __restrict__ lbuf,
                  unsigned* __restrict__ counter, uint4* __restrict__ entries) {
  int bid = blockIdx.x;
  int seg = bid & (NSEG_ - 1);
  int t   = bid >> 3;
  int mt  = t % MTILES_;
  int b   = t / MTILES_;
  int mc = qcnt[b];
  if (mt * MT_ >= mc) return;
  int nc = ncnt[b];
  int ntiles = (nc + NT_ - 1) / NT_;
  int t0 = (ntiles * seg) / NSEG_;
  int t1 = (ntiles * (seg + 1)) / NSEG_;
  if (t0 >= t1) return;

  __shared__ float Qs[DK_][MT_];
  __shared__ float Ks[DK_][NT_];
  __shared__ int Morig[MT_];
  __shared__ int Norig[NT_];
  __shared__ unsigned colkey[MT_];
  __shared__ float Mdec[MT_];
  __shared__ float lsh[MT_];

  int tid = threadIdx.x;
  int tc = tid & 15, tr = tid >> 4;

  // stage Q tile (gather compacted columns, fold p_scalar=40)
  for (int idx = tid; idx < DK_ * MT_; idx += 256) {
    int d = idx >> 6, c = idx & 63;
    int cm = mt * MT_ + c;
    int col = (cm < mc) ? qlist[b * M_ + cm] : qlist[b * M_];  // clamp -> duplicate of a valid col
    if (d == 0) Morig[c] = (cm < mc) ? col : -1;
    Qs[d][c] = 40.0f * qkey[(b * DK_ + d) * M_ + col];
  }
  if (tid < MT_) { colkey[tid] = 0u; lsh[tid] = 0.0f; }
  __syncthreads();
  if (PHASE == 2 && tid < MT_) {
    int cm = mt * MT_ + tid;
    Mdec[tid] = (cm < mc) ? fdec(maxkey[b * M_ + Morig[tid]]) : 0.0f;
  }

  float dl[4] = {0.f, 0.f, 0.f, 0.f};

  for (int tt = t0; tt < t1; ++tt) {
    int nbase = tt * NT_;
    __syncthreads();
    for (int idx = tid; idx < DK_ * NT_; idx += 256) {
      int d = idx >> 6, j = idx & 63;
      int jn = nbase + j;
      int ncol = (jn < nc) ? nlist[b * N_ + jn] : nlist[b * N_];  // clamp -> duplicate (harmless for max, guarded in ph2)
      if (d == 0) Norig[j] = (jn < nc) ? ncol : -1;
      Ks[d][j] = mkey[(b * DK_ + d) * N_ + ncol];
    }
    __syncthreads();
    float s[4][4] = {};
    #pragma unroll 8
    for (int k = 0; k < DK_; ++k) {
      float4 av = *(const float4*)&Ks[k][4 * tr];
      float4 bv = *(const float4*)&Qs[k][4 * tc];
      s[0][0] += av.x * bv.x; s[0][1] += av.x * bv.y; s[0][2] += av.x * bv.z; s[0][3] += av.x * bv.w;
      s[1][0] += av.y * bv.x; s[1][1] += av.y * bv.y; s[1][2] += av.y * bv.z; s[1][3] += av.y * bv.w;
      s[2][0] += av.z * bv.x; s[2][1] += av.z * bv.y; s[2][2] += av.z * bv.z; s[2][3] += av.z * bv.w;
      s[3][0] += av.w * bv.x; s[3][1] += av.w * bv.y; s[3][2] += av.w * bv.z; s[3][3] += av.w * bv.w;
    }
    if (PHASE == 1) {
      #pragma unroll
      for (int j = 0; j < 4; ++j) {
        float mx = fmaxf(fmaxf(s[0][j], s[1][j]), fmaxf(s[2][j], s[3][j]));
        atomicMax(&colkey[4 * tc + j], fkey(mx));
      }
    } else {
      #pragma unroll
      for (int i = 0; i < 4; ++i) {
        int nr = Norig[4 * tr + i];
        if (nr < 0) continue;
        #pragma unroll
        for (int j = 0; j < 4; ++j) {
          int c = 4 * tc + j;
          if (mt * MT_ + c >= mc) continue;
          float sv = s[i][j];
          float Mv = Mdec[c];
          if (sv >= Mv - TH_) {
            float e = expf(sv - Mv);
            dl[j] += e;
            unsigned id = atomicAdd(counter, 1u);
            if (id < CAP_)
              entries[id] = make_uint4(((unsigned)b << 20) | (unsigned)Morig[c],
                                       (unsigned)nr, __float_as_uint(e), 0u);
          }
        }
      }
    }
  }
  __syncthreads();
  if (PHASE == 1) {
    if (tid < MT_ && mt * MT_ + tid < mc)
      atomicMax(&maxkey[b * M_ + Morig[tid]], colkey[tid]);
  } else {
    #pragma unroll
    for (int j = 0; j < 4; ++j)
      if (dl[j] > 0.f) atomicAdd(&lsh[4 * tc + j], dl[j]);
    __syncthreads();
    if (tid < MT_ && mt * MT_ + tid < mc) {
      float lv = lsh[tid];
      if (lv > 0.f) atomicAdd(&lbuf[b * M_ + Morig[tid]], lv);
    }
  }
}

// ---- sparse PV: one wave per surviving (b,m,n,e) entry ----
__global__ __launch_bounds__(256)
void pv_kernel(const float* __restrict__ mval, const uint4* __restrict__ entries,
               const unsigned* __restrict__ counter, float* __restrict__ out) {
  unsigned cntu = *counter;
  int cnt = (int)((cntu < (unsigned)CAP_) ? cntu : (unsigned)CAP_);
  int gw = (int)((blockIdx.x * blockDim.x + threadIdx.x) >> 6);
  int lane = threadIdx.x & 63;
  int nw = (int)((gridDim.x * blockDim.x) >> 6);
  for (int ei = gw; ei < cnt; ei += nw) {
    uint4 en = entries[ei];
    int b = (int)(en.x >> 20);
    int m = (int)(en.x & 0xFFFFFu);
    int n = (int)en.y;
    float e = __uint_as_float(en.z);
    #pragma unroll
    for (int r = 0; r < 8; ++r) {
      int dv = r * 64 + lane;
      atomicAdd(&out[(size_t)(b * DV_ + dv) * M_ + m],
                e * mval[(size_t)(b * DV_ + dv) * N_ + n]);
    }
  }
}

// ---- divide by denominator, zero already guaranteed elsewhere ----
__global__ __launch_bounds__(256)
void finalize_kernel(const int* __restrict__ qmask, const float* __restrict__ lbuf,
                     float* __restrict__ out) {
  int total = B_ * DV_ * M_;
  int stride = gridDim.x * blockDim.x;
  for (int idx = blockIdx.x * blockDim.x + threadIdx.x; idx < total; idx += stride) {
    int m = idx % M_;
    int b = idx / (DV_ * M_);
    int bm = b * M_ + m;
    if (qmask[bm] == 0) continue;            // stays 0
    float l = lbuf[bm];
    out[idx] = (l > 0.f) ? out[idx] * (1.0f / l) : 0.0f;
  }
}

extern "C" void kernel_launch(void* const* d_in, const int* in_sizes, int n_in,
                              void* d_out, int out_size, void* d_ws, size_t ws_size,
                              hipStream_t stream) {
  const float* qkey  = (const float*)d_in[0];
  const int*   qmask = (const int*)d_in[1];
  const float* mkey  = (const float*)d_in[2];
  const float* mval  = (const float*)d_in[3];
  const int*   mmask = (const int*)d_in[4];
  float* out = (float*)d_out;

  uint8_t* w = (uint8_t*)d_ws;
  // layout: [maxkey B*M u32][lbuf B*M f32][counter+qcnt+ncnt pad to 200832][qlist][nlist][entries]
  unsigned* maxkey  = (unsigned*)(w + 0);
  float*    lbuf    = (float*)(w + 100352);
  unsigned* counter = (unsigned*)(w + 200704);
  int*      qcnt    = (int*)(w + 200720);
  int*      ncnt    = (int*)(w + 200752);
  int*      qlist   = (int*)(w + 200832);
  int*      nlist   = (int*)(w + 301184);
  uint4*    entries = (uint4*)(w + 501888);

  hipMemsetAsync(d_out, 0, (size_t)out_size * sizeof(float), stream);
  hipMemsetAsync(d_ws, 0, 200832, stream);

  scan_masks<<<B_, 256, 0, stream>>>(qmask, mmask, qlist, nlist, qcnt, ncnt);

  dim3 sg(B_ * MTILES_ * NSEG_);
  score_kernel<1><<<sg, 256, 0, stream>>>(qkey, mkey, qlist, nlist, qcnt, ncnt,
                                          maxkey, lbuf, counter, entries);
  score_kernel<2><<<sg, 256, 0, stream>>>(qkey, mkey, qlist, nlist, qcnt, ncnt,
                                          maxkey, lbuf, counter, entries);

  pv_kernel<<<1024, 256, 0, stream>>>(mval, entries, counter, out);
  finalize_kernel<<<2048, 256, 0, stream>>>(qmask, lbuf, out);
}

// Round 2
// 457.119 us; speedup vs baseline: 2.2846x; 2.2846x over previous
//
#include <hip/hip_runtime.h>
#include <stdint.h>

#define B_    8
#define DK_   128
#define DV_   512
#define M_    3136      // H*W
#define N_    6272      // T*H*W
#define MTILES_ 49      // 3136/64 exact
#define NSEG_ 8
#define TH_   30.0f

// ---- monotone float<->uint key for atomicMax on floats ----
__device__ __forceinline__ unsigned fkey(float x) {
  unsigned u = __float_as_uint(x);
  return (u & 0x80000000u) ? ~u : (u | 0x80000000u);
}
__device__ __forceinline__ float fdec(unsigned k) {
  return __uint_as_float((k & 0x80000000u) ? (k & 0x7fffffffu) : ~k);
}

// ---- per-batch deterministic compaction of qmask/mmask ----
__global__ __launch_bounds__(256)
void scan_masks(const int* __restrict__ qmask, const int* __restrict__ mmask,
                int* __restrict__ qlist, int* __restrict__ nlist,
                int* __restrict__ qcnt, int* __restrict__ ncnt) {
  int b = blockIdx.x;
  int tid = threadIdx.x, lane = tid & 63, wv = tid >> 6;
  __shared__ int wsum[4];
  __shared__ int cbase;
  if (tid == 0) cbase = 0;
  __syncthreads();
  for (int base = 0; base < M_; base += 256) {
    int i = base + tid;
    int flag = (i < M_) ? (qmask[b * M_ + i] != 0) : 0;
    unsigned long long bal = __ballot(flag);
    int prefix = __popcll(bal & ((1ull << lane) - 1ull));
    if (lane == 0) wsum[wv] = __popcll(bal);
    __syncthreads();
    int woff = 0;
    for (int t = 0; t < wv; ++t) woff += wsum[t];
    int total = wsum[0] + wsum[1] + wsum[2] + wsum[3];
    if (flag) qlist[b * M_ + cbase + woff + prefix] = i;
    __syncthreads();
    if (tid == 0) cbase += total;
    __syncthreads();
  }
  if (tid == 0) { qcnt[b] = cbase; cbase = 0; }
  __syncthreads();
  for (int base = 0; base < N_; base += 256) {
    int i = base + tid;
    int flag = (i < N_) ? (mmask[b * N_ + i] != 0) : 0;
    unsigned long long bal = __ballot(flag);
    int prefix = __popcll(bal & ((1ull << lane) - 1ull));
    if (lane == 0) wsum[wv] = __popcll(bal);
    __syncthreads();
    int woff = 0;
    for (int t = 0; t < wv; ++t) woff += wsum[t];
    int total = wsum[0] + wsum[1] + wsum[2] + wsum[3];
    if (flag) nlist[b * N_ + cbase + woff + prefix] = i;
    __syncthreads();
    if (tid == 0) cbase += total;
    __syncthreads();
  }
  if (tid == 0) ncnt[b] = cbase;
}

// ---- transpose mval [B,Dv,N] -> mvalT [B,N,Dv] (tier A only) ----
__global__ __launch_bounds__(256)
void transpose_mval(const float* __restrict__ mval, float* __restrict__ mvalT) {
  __shared__ float T[64][65];
  int b = blockIdx.z, dvt = blockIdx.y, nt = blockIdx.x;
  int lane = threadIdx.x & 63, ri = threadIdx.x >> 6;
  #pragma unroll
  for (int k = 0; k < 16; ++k) {
    int dvl = ri * 16 + k;
    T[dvl][lane] = mval[(size_t)(b * DV_ + dvt * 64 + dvl) * N_ + nt * 64 + lane];
  }
  __syncthreads();
  #pragma unroll
  for (int k = 0; k < 16; ++k) {
    int nl = ri * 16 + k;
    mvalT[(size_t)(b * N_ + nt * 64 + nl) * DV_ + dvt * 64 + lane] = T[lane][nl];
  }
}

// ---- single-pass score GEMM: exact column max + speculative (n, s) appends ----
template <int S>
__global__ __launch_bounds__(256)
void score_kernel(const float* __restrict__ qkey, const float* __restrict__ mkey,
                  const int* __restrict__ qlist, const int* __restrict__ nlist,
                  const int* __restrict__ qcnt, const int* __restrict__ ncnt,
                  unsigned* __restrict__ maxkey, unsigned* __restrict__ bcnt,
                  uint2* __restrict__ bucket) {
  int bid = blockIdx.x;
  int seg = bid & (NSEG_ - 1);
  int t   = bid >> 3;
  int mt  = t % MTILES_;
  int b   = t / MTILES_;
  int mc = qcnt[b];
  if (mt * 64 >= mc) return;
  int nc = ncnt[b];
  int ntiles = (nc + 63) / 64;
  int t0 = (ntiles * seg) / NSEG_;
  int t1 = (ntiles * (seg + 1)) / NSEG_;
  if (t0 >= t1) return;

  __shared__ float Qs[DK_][64];
  __shared__ float Ks[DK_][64];
  __shared__ int Morig[64];
  __shared__ int Norig[64];
  __shared__ unsigned runkey[64];   // running column-max key (block-local, merged w/ global)

  int tid = threadIdx.x;
  int tc = tid & 15, tr = tid >> 4;

  for (int idx = tid; idx < DK_ * 64; idx += 256) {
    int d = idx >> 6, c = idx & 63;
    int cm = mt * 64 + c;
    int col = (cm < mc) ? qlist[b * M_ + cm] : qlist[b * M_];
    if (d == 0) Morig[c] = (cm < mc) ? col : -1;
    Qs[d][c] = 40.0f * qkey[(b * DK_ + d) * M_ + col];
  }
  if (tid < 64) runkey[tid] = fkey(-3.0e38f);
  __syncthreads();

  for (int tt = t0; tt < t1; ++tt) {
    int nbase = tt * 64;
    for (int idx = tid; idx < DK_ * 64; idx += 256) {
      int d = idx >> 6, j = idx & 63;
      int jn = nbase + j;
      int ncol = (jn < nc) ? nlist[b * N_ + jn] : nlist[b * N_];
      if (d == 0) Norig[j] = (jn < nc) ? ncol : -1;
      Ks[d][j] = mkey[(b * DK_ + d) * N_ + ncol];
    }
    __syncthreads();
    float s[4][4] = {};
    #pragma unroll 8
    for (int k = 0; k < DK_; ++k) {
      float4 av = *(const float4*)&Ks[k][4 * tr];
      float4 bv = *(const float4*)&Qs[k][4 * tc];
      s[0][0] += av.x * bv.x; s[0][1] += av.x * bv.y; s[0][2] += av.x * bv.z; s[0][3] += av.x * bv.w;
      s[1][0] += av.y * bv.x; s[1][1] += av.y * bv.y; s[1][2] += av.y * bv.z; s[1][3] += av.y * bv.w;
      s[2][0] += av.z * bv.x; s[2][1] += av.z * bv.y; s[2][2] += av.z * bv.z; s[2][3] += av.z * bv.w;
      s[3][0] += av.w * bv.x; s[3][1] += av.w * bv.y; s[3][2] += av.w * bv.z; s[3][3] += av.w * bv.w;
    }
    // exact tile-local column max -> running key -> global key
    #pragma unroll
    for (int j = 0; j < 4; ++j) {
      float mx = fmaxf(fmaxf(s[0][j], s[1][j]), fmaxf(s[2][j], s[3][j]));
      atomicMax(&runkey[4 * tc + j], fkey(mx));
    }
    __syncthreads();
    if (tid < 64 && Morig[tid] >= 0) {
      unsigned mine = runkey[tid];
      unsigned old = atomicMax(&maxkey[b * M_ + Morig[tid]], mine);
      if (old > mine) runkey[tid] = old;   // import other blocks' progress
    }
    __syncthreads();
    // speculative append: superset of {s >= final_max - TH}, filtered exactly in PV
    #pragma unroll
    for (int j = 0; j < 4; ++j) {
      int c = 4 * tc + j;
      int mo = Morig[c];
      if (mo < 0) continue;
      float thr = fdec(runkey[c]) - TH_;
      #pragma unroll
      for (int i = 0; i < 4; ++i) {
        int nr = Norig[4 * tr + i];
        if (nr < 0) continue;
        float sv = s[i][j];
        if (sv >= thr) {
          unsigned slot = atomicAdd(&bcnt[b * M_ + mo], 1u);
          if (slot < (unsigned)S)
            bucket[(size_t)(b * M_ + mo) * S + slot] =
                make_uint2((unsigned)nr, __float_as_uint(sv));
        }
      }
    }
    __syncthreads();
  }
}

// ---- PV: one wave per active query column; filter+softmax+accumulate, no atomics ----
template <int S, bool TA>
__global__ __launch_bounds__(256)
void pv_kernel(const float* __restrict__ mval, const float* __restrict__ mvalT,
               const float* __restrict__ qkey, const float* __restrict__ mkey,
               const int* __restrict__ qlist, const int* __restrict__ qcnt,
               const int* __restrict__ nlist, const int* __restrict__ ncnt,
               const unsigned* __restrict__ maxkey, const unsigned* __restrict__ bcnt,
               const uint2* __restrict__ bucket, float* __restrict__ outp) {
  __shared__ float qsh[4][DK_];
  int b = blockIdx.y;
  int wv = threadIdx.x >> 6, lane = threadIdx.x & 63;
  int c = blockIdx.x * 4 + wv;
  if (c >= qcnt[b]) return;
  int m = qlist[b * M_ + c];
  float Mx = fdec(maxkey[b * M_ + m]);
  unsigned cnt = bcnt[b * M_ + m];
  float acc[8] = {0, 0, 0, 0, 0, 0, 0, 0};
  float lpart = 0.f;

  if (cnt <= (unsigned)S) {
    // normal path: bucket holds every candidate
    uint2 en = make_uint2(0u, 0u);
    if (lane < (int)cnt) en = bucket[(size_t)(b * M_ + m) * S + lane];
    float sv = __uint_as_float(en.y);
    float e = (lane < (int)cnt && sv >= Mx - TH_) ? expf(sv - Mx) : 0.f;
    lpart = e;
    unsigned long long alive = __ballot(e > 0.f);
    while (alive) {
      int lb = __ffsll((unsigned long long)alive) - 1;
      alive &= alive - 1;
      float w = __shfl(e, lb);
      int nn = __shfl((int)en.x, lb);
      #pragma unroll
      for (int r = 0; r < 8; ++r)
        acc[r] += w * (TA ? mvalT[(size_t)(b * N_ + nn) * DV_ + r * 64 + lane]
                          : mval[(size_t)(b * DV_ + r * 64 + lane) * N_ + nn]);
    }
  } else {
    // overflow fallback (expected never): exact recompute of this column
    for (int d = lane; d < DK_; d += 64)
      qsh[wv][d] = 40.0f * qkey[(b * DK_ + d) * M_ + m];
    int nc = ncnt[b];
    for (int base = 0; base < nc; base += 64) {
      int jn = base + lane;
      int nn = (jn < nc) ? nlist[b * N_ + jn] : -1;
      float sv = -3.0e38f;
      if (nn >= 0) {
        float a = 0.f;
        for (int d = 0; d < DK_; ++d)
          a += qsh[wv][d] * mkey[(size_t)(b * DK_ + d) * N_ + nn];
        sv = a;
      }
      float e = (sv >= Mx - TH_) ? expf(sv - Mx) : 0.f;
      lpart += e;
      unsigned long long alive = __ballot(e > 0.f);
      while (alive) {
        int lb = __ffsll((unsigned long long)alive) - 1;
        alive &= alive - 1;
        float w = __shfl(e, lb);
        int n2 = __shfl(nn, lb);
        #pragma unroll
        for (int r = 0; r < 8; ++r)
          acc[r] += w * (TA ? mvalT[(size_t)(b * N_ + n2) * DV_ + r * 64 + lane]
                            : mval[(size_t)(b * DV_ + r * 64 + lane) * N_ + n2]);
      }
    }
  }
  // wave-reduce denominator, normalize, write
  float l = lpart;
  #pragma unroll
  for (int off = 32; off > 0; off >>= 1) l += __shfl_xor(l, off);
  float inv = (l > 0.f) ? 1.0f / l : 0.0f;
  #pragma unroll
  for (int r = 0; r < 8; ++r) {
    float v = acc[r] * inv;
    if (TA) outp[(size_t)(b * M_ + m) * DV_ + r * 64 + lane] = v;
    else    outp[(size_t)(b * DV_ + r * 64 + lane) * M_ + m] = v;
  }
}

// ---- tier A: transpose outT [B,M,Dv] -> out [B,Dv,M], applying qmask ----
__global__ __launch_bounds__(256)
void finalize_T(const float* __restrict__ outT, const int* __restrict__ qmask,
                float* __restrict__ out) {
  __shared__ float T[64][65];
  int b = blockIdx.z, dvt = blockIdx.y, mt = blockIdx.x;
  int lane = threadIdx.x & 63, ri = threadIdx.x >> 6;
  #pragma unroll
  for (int k = 0; k < 16; ++k) {
    int ml = ri * 16 + k;
    int m = mt * 64 + ml;
    bool act = (qmask[b * M_ + m] != 0);
    T[ml][lane] = act ? outT[(size_t)(b * M_ + m) * DV_ + dvt * 64 + lane] : 0.f;
  }
  __syncthreads();
  #pragma unroll
  for (int k = 0; k < 16; ++k) {
    int dvl = ri * 16 + k;
    out[(size_t)(b * DV_ + dvt * 64 + dvl) * M_ + mt * 64 + lane] = T[lane][dvl];
  }
}

extern "C" void kernel_launch(void* const* d_in, const int* in_sizes, int n_in,
                              void* d_out, int out_size, void* d_ws, size_t ws_size,
                              hipStream_t stream) {
  const float* qkey  = (const float*)d_in[0];
  const int*   qmask = (const int*)d_in[1];
  const float* mkey  = (const float*)d_in[2];
  const float* mval  = (const float*)d_in[3];
  const int*   mmask = (const int*)d_in[4];
  float* out = (float*)d_out;

  uint8_t* w = (uint8_t*)d_ws;
  unsigned* maxkey = (unsigned*)(w + 0);            // B*M u32
  unsigned* bcnt   = (unsigned*)(w + 100352);       // B*M u32
  int*      qcnt   = (int*)(w + 200704);
  int*      ncnt   = (int*)(w + 200736);
  int*      qlist  = (int*)(w + 200832);            // B*M int
  int*      nlist  = (int*)(w + 301184);            // B*N int
  uint2*    bucket = (uint2*)(w + 501888);

  const size_t SZ_BUCKET_A = (size_t)B_ * M_ * 64 * 8;   // 12,845,056
  const size_t SZ_OUTT     = (size_t)B_ * M_ * DV_ * 4;  // 51,380,224
  const size_t SZ_MVALT    = (size_t)B_ * N_ * DV_ * 4;  // 102,760,448
  const size_t NEED_A = 501888 + SZ_BUCKET_A + SZ_OUTT + SZ_MVALT;
  bool tierA = (ws_size >= NEED_A);

  float* outT  = (float*)(w + 501888 + SZ_BUCKET_A);
  float* mvalT = (float*)(w + 501888 + SZ_BUCKET_A + SZ_OUTT);

  hipMemsetAsync(d_ws, 0, 200832, stream);   // maxkey + bcnt (+counts, rewritten)

  scan_masks<<<B_, 256, 0, stream>>>(qmask, mmask, qlist, nlist, qcnt, ncnt);

  dim3 sg(B_ * MTILES_ * NSEG_);
  if (tierA) {
    transpose_mval<<<dim3(N_ / 64, DV_ / 64, B_), 256, 0, stream>>>(mval, mvalT);
    score_kernel<64><<<sg, 256, 0, stream>>>(qkey, mkey, qlist, nlist, qcnt, ncnt,
                                             maxkey, bcnt, bucket);
    pv_kernel<64, true><<<dim3((M_ + 255) / 256 * 64, B_), 256, 0, stream>>>(
        mval, mvalT, qkey, mkey, qlist, qcnt, nlist, ncnt, maxkey, bcnt, bucket, outT);
    finalize_T<<<dim3(MTILES_, DV_ / 64, B_), 256, 0, stream>>>(outT, qmask, out);
  } else {
    hipMemsetAsync(d_out, 0, (size_t)out_size * sizeof(float), stream);
    score_kernel<16><<<sg, 256, 0, stream>>>(qkey, mkey, qlist, nlist, qcnt, ncnt,
                                             maxkey, bcnt, bucket);
    pv_kernel<16, false><<<dim3((M_ + 255) / 256 * 64, B_), 256, 0, stream>>>(
        mval, mvalT, qkey, mkey, qlist, qcnt, nlist, ncnt, maxkey, bcnt, bucket, out);
  }
}

// Round 3
// 229.591 us; speedup vs baseline: 4.5488x; 1.9910x over previous
//
#include <hip/hip_runtime.h>
#include <stdint.h>

#define B_    8
#define DK_   128
#define DV_   512
#define M_    3136      // H*W
#define N_    6272      // T*H*W
#define MTILES_ 49      // 3136/64 exact
#define NSEG_ 8
#define TH_   30.0f
#define MARGIN_ 36.0f
#define BKT_  64

typedef short bf16x8 __attribute__((ext_vector_type(8)));
typedef float f32x16 __attribute__((ext_vector_type(16)));
typedef unsigned short u16x8 __attribute__((ext_vector_type(8)));

// ---- monotone float<->uint key for atomicMax on floats ----
__device__ __forceinline__ unsigned fkey(float x) {
  unsigned u = __float_as_uint(x);
  return (u & 0x80000000u) ? ~u : (u | 0x80000000u);
}
__device__ __forceinline__ float fdec(unsigned k) {
  return __uint_as_float((k & 0x80000000u) ? (k & 0x7fffffffu) : ~k);
}
// fp32 -> bf16 (RNE)
__device__ __forceinline__ unsigned short f2bf(float x) {
  unsigned u = __float_as_uint(x);
  return (unsigned short)((u + 0x7fffu + ((u >> 16) & 1u)) >> 16);
}
__device__ __forceinline__ unsigned pk2(float x, float y) {
  return (unsigned)f2bf(x) | ((unsigned)f2bf(y) << 16);
}
__device__ __forceinline__ float bf2f(unsigned short h) {
  return __uint_as_float(((unsigned)h) << 16);
}

// ---- per-batch deterministic compaction of qmask/mmask ----
__global__ __launch_bounds__(256)
void scan_masks(const int* __restrict__ qmask, const int* __restrict__ mmask,
                int* __restrict__ qlist, int* __restrict__ nlist,
                int* __restrict__ qcnt, int* __restrict__ ncnt) {
  int b = blockIdx.x;
  int tid = threadIdx.x, lane = tid & 63, wv = tid >> 6;
  __shared__ int wsum[4];
  __shared__ int cbase;
  if (tid == 0) cbase = 0;
  __syncthreads();
  for (int base = 0; base < M_; base += 256) {
    int i = base + tid;
    int flag = (i < M_) ? (qmask[b * M_ + i] != 0) : 0;
    unsigned long long bal = __ballot(flag);
    int prefix = __popcll(bal & ((1ull << lane) - 1ull));
    if (lane == 0) wsum[wv] = __popcll(bal);
    __syncthreads();
    int woff = 0;
    for (int t = 0; t < wv; ++t) woff += wsum[t];
    int total = wsum[0] + wsum[1] + wsum[2] + wsum[3];
    if (flag) qlist[b * M_ + cbase + woff + prefix] = i;
    __syncthreads();
    if (tid == 0) cbase += total;
    __syncthreads();
  }
  if (tid == 0) { qcnt[b] = cbase; cbase = 0; }
  __syncthreads();
  for (int base = 0; base < N_; base += 256) {
    int i = base + tid;
    int flag = (i < N_) ? (mmask[b * N_ + i] != 0) : 0;
    unsigned long long bal = __ballot(flag);
    int prefix = __popcll(bal & ((1ull << lane) - 1ull));
    if (lane == 0) wsum[wv] = __popcll(bal);
    __syncthreads();
    int woff = 0;
    for (int t = 0; t < wv; ++t) woff += wsum[t];
    int total = wsum[0] + wsum[1] + wsum[2] + wsum[3];
    if (flag) nlist[b * N_ + cbase + woff + prefix] = i;
    __syncthreads();
    if (tid == 0) cbase += total;
    __syncthreads();
  }
  if (tid == 0) ncnt[b] = cbase;
}

// ---- transpose key [B][128][X] -> [B][X][128] (fp32, optional scale) ----
__global__ __launch_bounds__(256)
void transpose_key(const float* __restrict__ src, float* __restrict__ dst,
                   int X, float scale) {
  __shared__ float T[64][65];
  int b = blockIdx.z, dt = blockIdx.y, xt = blockIdx.x;
  int lane = threadIdx.x & 63, ri = threadIdx.x >> 6;
  #pragma unroll
  for (int k = 0; k < 16; ++k) {
    int dl = ri * 16 + k;
    T[dl][lane] = src[((size_t)b * DK_ + dt * 64 + dl) * X + xt * 64 + lane];
  }
  __syncthreads();
  #pragma unroll
  for (int k = 0; k < 16; ++k) {
    int xl = ri * 16 + k;
    dst[((size_t)b * X + xt * 64 + xl) * DK_ + dt * 64 + lane] = scale * T[lane][xl];
  }
}

// ---- transpose mval [B][512][N] -> bf16 [B][N][512] ----
__global__ __launch_bounds__(256)
void transpose_val(const float* __restrict__ mval, unsigned short* __restrict__ mvalT) {
  __shared__ float T[64][65];
  int b = blockIdx.z, dvt = blockIdx.y, nt = blockIdx.x;
  int lane = threadIdx.x & 63, ri = threadIdx.x >> 6;
  #pragma unroll
  for (int k = 0; k < 16; ++k) {
    int dvl = ri * 16 + k;
    T[dvl][lane] = mval[((size_t)b * DV_ + dvt * 64 + dvl) * N_ + nt * 64 + lane];
  }
  __syncthreads();
  #pragma unroll
  for (int k = 0; k < 16; ++k) {
    int nl = ri * 16 + k;
    mvalT[((size_t)b * N_ + nt * 64 + nl) * DV_ + dvt * 64 + lane] = f2bf(T[lane][nl]);
  }
}

// ---- bf16-MFMA approximate score GEMM: running max + candidate appends ----
__global__ __launch_bounds__(256, 4)
void score_mfma(const float* __restrict__ qkeyT, const float* __restrict__ mkeyT,
                const int* __restrict__ qlist, const int* __restrict__ nlist,
                const int* __restrict__ qcnt, const int* __restrict__ ncnt,
                unsigned* __restrict__ maxkey, unsigned* __restrict__ bcnt,
                unsigned* __restrict__ bucket) {
  int bid = blockIdx.x;
  int seg = bid & (NSEG_ - 1);
  int t   = bid >> 3;
  int mt  = t % MTILES_;
  int b   = t / MTILES_;
  int mc = qcnt[b];
  if (mt * 64 >= mc) return;
  int nc = ncnt[b];
  int ntiles = (nc + 63) >> 6;
  int t0 = (ntiles * seg) / NSEG_;
  int t1 = (ntiles * (seg + 1)) / NSEG_;
  if (t0 >= t1) return;

  __shared__ unsigned short Qs[64 * 128];   // bf16, [row][k], XOR-swizzled
  __shared__ unsigned short Ks[64 * 128];
  __shared__ int Morig[64];
  __shared__ int Norig[64];
  __shared__ unsigned runkey[64];
  char* Qsb = (char*)Qs;
  char* Ksb = (char*)Ks;

  int tid = threadIdx.x;
  int lane = tid & 63, wv = tid >> 6;
  int wn = wv & 1, wm = wv >> 1;
  int l31 = lane & 31, lhi = lane >> 5;

  // stage Q tile: qkeyT rows (40x prefolded) -> bf16 swizzled LDS
  for (int i = tid; i < 2048; i += 256) {
    int row = i >> 5;
    int k4 = (i & 31) << 2;                       // float index, step 4
    int cm = mt * 64 + row;
    int col = (cm < mc) ? qlist[b * M_ + cm] : qlist[b * M_];
    if (k4 == 0) Morig[row] = (cm < mc) ? col : -1;
    float4 v = *(const float4*)&qkeyT[((size_t)b * M_ + col) * DK_ + k4];
    uint2 w;
    w.x = pk2(v.x, v.y);
    w.y = pk2(v.z, v.w);
    *(uint2*)(Qsb + (row << 8) + (((unsigned)(k4 << 1)) ^ ((row & 7) << 4))) = w;
  }
  if (tid < 64) runkey[tid] = 0u;   // below every fkey(real score)
  __syncthreads();

  int arow = wn * 32 + l31;          // K-tile row (n_local)
  int brow = wm * 32 + l31;          // Q-tile row (m_local)
  int klo  = lhi << 4;               // byte offset of lane's k-group
  int aswz = (arow & 7) << 4;
  int bswz = (brow & 7) << 4;

  for (int tt = t0; tt < t1; ++tt) {
    int nbase = tt << 6;
    for (int i = tid; i < 2048; i += 256) {
      int row = i >> 5;
      int k4 = (i & 31) << 2;
      int jn = nbase + row;
      int ncol = (jn < nc) ? nlist[b * N_ + jn] : nlist[b * N_];
      if (k4 == 0) Norig[row] = (jn < nc) ? ncol : -1;
      float4 v = *(const float4*)&mkeyT[((size_t)b * N_ + ncol) * DK_ + k4];
      uint2 w;
      w.x = pk2(v.x, v.y);
      w.y = pk2(v.z, v.w);
      *(uint2*)(Ksb + (row << 8) + (((unsigned)(k4 << 1)) ^ ((row & 7) << 4))) = w;
    }
    __syncthreads();

    f32x16 acc;
    #pragma unroll
    for (int r = 0; r < 16; ++r) acc[r] = 0.0f;
    #pragma unroll
    for (int kc = 0; kc < 8; ++kc) {
      int koff = (kc << 5) | klo;
      bf16x8 af = *(const bf16x8*)(Ksb + (arow << 8) + (koff ^ aswz));
      bf16x8 bq = *(const bf16x8*)(Qsb + (brow << 8) + (koff ^ bswz));
      acc = __builtin_amdgcn_mfma_f32_32x32x16_bf16(af, bq, acc, 0, 0, 0);
    }

    // per-column (m) max: 16 regs -> lane pair (l, l+32) -> LDS runkey
    float cmx = acc[0];
    #pragma unroll
    for (int r = 1; r < 16; ++r) cmx = fmaxf(cmx, acc[r]);
    cmx = fmaxf(cmx, __shfl_xor(cmx, 32));
    if (lane < 32) atomicMax(&runkey[wm * 32 + l31], fkey(cmx));
    __syncthreads();
    // merge with global progress (monotone; threshold only tightens)
    if (tid < 64 && Morig[tid] >= 0) {
      unsigned mine = runkey[tid];
      unsigned old = atomicMax(&maxkey[b * M_ + Morig[tid]], mine);
      if (old > mine) runkey[tid] = old;
    }
    __syncthreads();
    // candidate appends (superset of {s_true >= max_true - TH})
    {
      int mloc = wm * 32 + l31;
      int mo = Morig[mloc];
      if (mo >= 0) {
        float thr = fdec(runkey[mloc]) - MARGIN_;
        #pragma unroll
        for (int r = 0; r < 16; ++r) {
          if (acc[r] >= thr) {
            int nl = wn * 32 + (r & 3) + ((r >> 2) << 3) + (lhi << 2);
            int no = Norig[nl];
            if (no >= 0) {
              unsigned slot = atomicAdd(&bcnt[b * M_ + mo], 1u);
              if (slot < (unsigned)BKT_)
                bucket[(((size_t)(b * M_ + mo)) << 6) + slot] = (unsigned)no;
            }
          }
        }
      }
    }
    __syncthreads();
  }
}

__device__ __forceinline__ float dot128(const float* __restrict__ q,
                                        const float* __restrict__ k) {
  float s = 0.f;
  #pragma unroll 8
  for (int i = 0; i < DK_; i += 4) {
    float4 a = *(const float4*)&q[i];
    float4 bb = *(const float4*)&k[i];
    s += a.x * bb.x + a.y * bb.y + a.z * bb.z + a.w * bb.w;
  }
  return s;
}

// ---- PV: one wave per active column; exact fp32 rescore of candidates ----
__global__ __launch_bounds__(256)
void pv_exact(const float* __restrict__ qkeyT, const float* __restrict__ mkeyT,
              const unsigned short* __restrict__ mvalT,
              const int* __restrict__ qlist, const int* __restrict__ qcnt,
              const int* __restrict__ nlist, const int* __restrict__ ncnt,
              const unsigned* __restrict__ bcnt, const unsigned* __restrict__ bucket,
              float* __restrict__ outT) {
  int b = blockIdx.y;
  int wv = threadIdx.x >> 6, lane = threadIdx.x & 63;
  int c = blockIdx.x * 4 + wv;
  if (c >= qcnt[b]) return;
  int m = qlist[b * M_ + c];
  unsigned cnt = bcnt[b * M_ + m];
  const float* qrow = qkeyT + ((size_t)b * M_ + m) * DK_;
  float acc[8] = {0.f, 0.f, 0.f, 0.f, 0.f, 0.f, 0.f, 0.f};
  float lsum = 0.f;

  if (cnt <= (unsigned)BKT_) {
    int n = -1;
    if (lane < (int)cnt) n = (int)bucket[(((size_t)(b * M_ + m)) << 6) + lane];
    float sv = -3.0e38f;
    if (n >= 0) sv = dot128(qrow, mkeyT + ((size_t)b * N_ + n) * DK_);
    float mx = sv;
    #pragma unroll
    for (int o = 32; o > 0; o >>= 1) mx = fmaxf(mx, __shfl_xor(mx, o));
    float e = (n >= 0 && sv >= mx - TH_) ? expf(sv - mx) : 0.f;
    lsum = e;
    #pragma unroll
    for (int o = 32; o > 0; o >>= 1) lsum += __shfl_xor(lsum, o);
    unsigned long long alive = __ballot(e > 0.f);
    while (alive) {
      int lb = __ffsll((unsigned long long)alive) - 1;
      alive &= alive - 1;
      float w = __shfl(e, lb);
      int nn = __shfl(n, lb);
      u16x8 vvv = *(const u16x8*)(mvalT + ((size_t)b * N_ + nn) * DV_ + lane * 8);
      #pragma unroll
      for (int r = 0; r < 8; ++r) acc[r] += w * bf2f(vvv[r]);
    }
  } else {
    // overflow fallback (statistically unreachable): exact two-pass
    int nc = ncnt[b];
    float mx = -3.0e38f;
    for (int base = 0; base < nc; base += 64) {
      int jn = base + lane;
      float sv = -3.0e38f;
      if (jn < nc) {
        int n = nlist[b * N_ + jn];
        sv = dot128(qrow, mkeyT + ((size_t)b * N_ + n) * DK_);
      }
      mx = fmaxf(mx, sv);
    }
    #pragma unroll
    for (int o = 32; o > 0; o >>= 1) mx = fmaxf(mx, __shfl_xor(mx, o));
    for (int base = 0; base < nc; base += 64) {
      int jn = base + lane;
      int n = -1;
      float sv = -3.0e38f;
      if (jn < nc) {
        n = nlist[b * N_ + jn];
        sv = dot128(qrow, mkeyT + ((size_t)b * N_ + n) * DK_);
      }
      float e = (n >= 0 && sv >= mx - TH_) ? expf(sv - mx) : 0.f;
      lsum += e;
      unsigned long long alive = __ballot(e > 0.f);
      while (alive) {
        int lb = __ffsll((unsigned long long)alive) - 1;
        alive &= alive - 1;
        float w = __shfl(e, lb);
        int nn = __shfl(n, lb);
        u16x8 vvv = *(const u16x8*)(mvalT + ((size_t)b * N_ + nn) * DV_ + lane * 8);
        #pragma unroll
        for (int r = 0; r < 8; ++r) acc[r] += w * bf2f(vvv[r]);
      }
    }
    #pragma unroll
    for (int o = 32; o > 0; o >>= 1) lsum += __shfl_xor(lsum, o);
  }

  float inv = (lsum > 0.f) ? 1.0f / lsum : 0.0f;
  float* op = outT + ((size_t)b * M_ + m) * DV_ + lane * 8;
  float4 o0 = make_float4(acc[0] * inv, acc[1] * inv, acc[2] * inv, acc[3] * inv);
  float4 o1 = make_float4(acc[4] * inv, acc[5] * inv, acc[6] * inv, acc[7] * inv);
  *(float4*)&op[0] = o0;
  *(float4*)&op[4] = o1;
}

// ---- transpose outT [B][M][Dv] -> out [B][Dv][M], applying qmask ----
__global__ __launch_bounds__(256)
void finalize_T(const float* __restrict__ outT, const int* __restrict__ qmask,
                float* __restrict__ out) {
  __shared__ float T[64][65];
  int b = blockIdx.z, dvt = blockIdx.y, mt = blockIdx.x;
  int lane = threadIdx.x & 63, ri = threadIdx.x >> 6;
  #pragma unroll
  for (int k = 0; k < 16; ++k) {
    int ml = ri * 16 + k;
    int m = mt * 64 + ml;
    bool act = (qmask[b * M_ + m] != 0);
    T[ml][lane] = act ? outT[((size_t)b * M_ + m) * DV_ + dvt * 64 + lane] : 0.f;
  }
  __syncthreads();
  #pragma unroll
  for (int k = 0; k < 16; ++k) {
    int dvl = ri * 16 + k;
    out[((size_t)b * DV_ + dvt * 64 + dvl) * M_ + mt * 64 + lane] = T[lane][dvl];
  }
}

extern "C" void kernel_launch(void* const* d_in, const int* in_sizes, int n_in,
                              void* d_out, int out_size, void* d_ws, size_t ws_size,
                              hipStream_t stream) {
  const float* qkey  = (const float*)d_in[0];
  const int*   qmask = (const int*)d_in[1];
  const float* mkey  = (const float*)d_in[2];
  const float* mval  = (const float*)d_in[3];
  const int*   mmask = (const int*)d_in[4];
  float* out = (float*)d_out;

  uint8_t* w = (uint8_t*)d_ws;
  unsigned*       maxkey = (unsigned*)(w + 0);          // B*M u32
  unsigned*       bcnt   = (unsigned*)(w + 100352);     // B*M u32
  int*            qcnt   = (int*)(w + 200704);
  int*            ncnt   = (int*)(w + 200736);
  int*            qlist  = (int*)(w + 200832);          // B*M
  int*            nlist  = (int*)(w + 301184);          // B*N
  unsigned*       bucket = (unsigned*)(w + 501888);     // B*M*64
  float*          qkeyT  = (float*)(w + 6924416);       // B*M*128 (x40 folded)
  float*          mkeyT  = (float*)(w + 19769472);      // B*N*128
  float*          outT   = (float*)(w + 45459584);      // B*M*512
  unsigned short* mvalT  = (unsigned short*)(w + 96839808); // B*N*512 bf16
  // end: 148,220,032 bytes (< proven-available workspace)

  hipMemsetAsync(d_ws, 0, 200832, stream);   // maxkey + bcnt + counts

  scan_masks<<<B_, 256, 0, stream>>>(qmask, mmask, qlist, nlist, qcnt, ncnt);
  transpose_key<<<dim3(M_ / 64, DK_ / 64, B_), 256, 0, stream>>>(qkey, qkeyT, M_, 40.0f);
  transpose_key<<<dim3(N_ / 64, DK_ / 64, B_), 256, 0, stream>>>(mkey, mkeyT, N_, 1.0f);
  transpose_val<<<dim3(N_ / 64, DV_ / 64, B_), 256, 0, stream>>>(mval, mvalT);

  score_mfma<<<B_ * MTILES_ * NSEG_, 256, 0, stream>>>(
      qkeyT, mkeyT, qlist, nlist, qcnt, ncnt, maxkey, bcnt, bucket);

  pv_exact<<<dim3((M_ + 3) / 4, B_), 256, 0, stream>>>(
      qkeyT, mkeyT, mvalT, qlist, qcnt, nlist, ncnt, bcnt, bucket, outT);

  finalize_T<<<dim3(M_ / 64, DV_ / 64, B_), 256, 0, stream>>>(outT, qmask, out);
}

// Round 4
// 212.250 us; speedup vs baseline: 4.9204x; 1.0817x over previous
//
#include <hip/hip_runtime.h>
#include <stdint.h>

#define B_    8
#define DK_   128
#define DV_   512
#define M_    3136      // H*W
#define N_    6272      // T*H*W
#define MT128_ 25       // ceil(3136/128): static grid covers any qcnt
#define NSEG_ 8
#define TH_   30.0f
#define MARGIN_ 36.0f
#define BKT_  64

typedef short bf16x8 __attribute__((ext_vector_type(8)));
typedef float f32x16 __attribute__((ext_vector_type(16)));
typedef unsigned short u16x8 __attribute__((ext_vector_type(8)));

// ---- monotone float<->uint key for atomicMax on floats ----
__device__ __forceinline__ unsigned fkey(float x) {
  unsigned u = __float_as_uint(x);
  return (u & 0x80000000u) ? ~u : (u | 0x80000000u);
}
__device__ __forceinline__ float fdec(unsigned k) {
  return __uint_as_float((k & 0x80000000u) ? (k & 0x7fffffffu) : ~k);
}
// fp32 -> bf16 (RNE)
__device__ __forceinline__ unsigned short f2bf(float x) {
  unsigned u = __float_as_uint(x);
  return (unsigned short)((u + 0x7fffu + ((u >> 16) & 1u)) >> 16);
}
__device__ __forceinline__ float bf2f(unsigned short h) {
  return __uint_as_float(((unsigned)h) << 16);
}

// ---- per-batch compaction; blockIdx.y selects qmask vs mmask ----
__global__ __launch_bounds__(256)
void scan_masks(const int* __restrict__ qmask, const int* __restrict__ mmask,
                int* __restrict__ qlist, int* __restrict__ nlist,
                int* __restrict__ qcnt, int* __restrict__ ncnt) {
  int b = blockIdx.x;
  int tid = threadIdx.x, lane = tid & 63, wv = tid >> 6;
  __shared__ int wsum[4];
  __shared__ int cbase;
  if (tid == 0) cbase = 0;
  __syncthreads();
  const int* src = (blockIdx.y == 0) ? (qmask + b * M_) : (mmask + b * N_);
  int* dst = (blockIdx.y == 0) ? (qlist + b * M_) : (nlist + b * N_);
  int len = (blockIdx.y == 0) ? M_ : N_;
  for (int base = 0; base < len; base += 256) {
    int i = base + tid;
    int flag = (i < len) ? (src[i] != 0) : 0;
    unsigned long long bal = __ballot(flag);
    int prefix = __popcll(bal & ((1ull << lane) - 1ull));
    if (lane == 0) wsum[wv] = __popcll(bal);
    __syncthreads();
    int woff = 0;
    for (int t = 0; t < wv; ++t) woff += wsum[t];
    int total = wsum[0] + wsum[1] + wsum[2] + wsum[3];
    if (flag) dst[cbase + woff + prefix] = i;
    __syncthreads();
    if (tid == 0) cbase += total;
    __syncthreads();
  }
  if (tid == 0) {
    if (blockIdx.y == 0) qcnt[b] = cbase; else ncnt[b] = cbase;
  }
}

// ---- transpose key [B][128][X] -> fp32 [B][X][128] AND bf16 [B][X][128] ----
__global__ __launch_bounds__(256)
void transpose_key(const float* __restrict__ src, float* __restrict__ dstf,
                   unsigned short* __restrict__ dstb, int X, float scale) {
  __shared__ float T[64][65];
  int b = blockIdx.z, dt = blockIdx.y, xt = blockIdx.x;
  int lane = threadIdx.x & 63, ri = threadIdx.x >> 6;
  #pragma unroll
  for (int k = 0; k < 16; ++k) {
    int dl = ri * 16 + k;
    T[dl][lane] = src[((size_t)b * DK_ + dt * 64 + dl) * X + xt * 64 + lane];
  }
  __syncthreads();
  #pragma unroll
  for (int k = 0; k < 16; ++k) {
    int xl = ri * 16 + k;
    float v = scale * T[lane][xl];
    size_t idx = ((size_t)b * X + xt * 64 + xl) * DK_ + dt * 64 + lane;
    dstf[idx] = v;
    dstb[idx] = f2bf(v);
  }
}

// ---- transpose mval [B][512][N] -> bf16 [B][N][512] ----
__global__ __launch_bounds__(256)
void transpose_val(const float* __restrict__ mval, unsigned short* __restrict__ mvalT) {
  __shared__ float T[64][65];
  int b = blockIdx.z, dvt = blockIdx.y, nt = blockIdx.x;
  int lane = threadIdx.x & 63, ri = threadIdx.x >> 6;
  #pragma unroll
  for (int k = 0; k < 16; ++k) {
    int dvl = ri * 16 + k;
    T[dvl][lane] = mval[((size_t)b * DV_ + dvt * 64 + dvl) * N_ + nt * 64 + lane];
  }
  __syncthreads();
  #pragma unroll
  for (int k = 0; k < 16; ++k) {
    int nl = ri * 16 + k;
    mvalT[((size_t)b * N_ + nt * 64 + nl) * DV_ + dvt * 64 + lane] = f2bf(T[lane][nl]);
  }
}

// ---- bf16-MFMA approximate score GEMM, 128m x 64n tiles, pre-packed bf16 ----
__global__ __launch_bounds__(256, 3)
void score_mfma(const unsigned short* __restrict__ qkb, const unsigned short* __restrict__ mkb,
                const int* __restrict__ qlist, const int* __restrict__ nlist,
                const int* __restrict__ qcnt, const int* __restrict__ ncnt,
                unsigned* __restrict__ maxkey, unsigned* __restrict__ bcnt,
                unsigned* __restrict__ bucket) {
  int bid = blockIdx.x;
  int seg = bid & (NSEG_ - 1);
  int t   = bid >> 3;
  int mt  = t % MT128_;
  int b   = t / MT128_;
  int mc = qcnt[b];
  if (mt * 128 >= mc) return;
  int nc = ncnt[b];
  int ntiles = (nc + 63) >> 6;
  int t0 = (ntiles * seg) / NSEG_;
  int t1 = (ntiles * (seg + 1)) / NSEG_;
  if (t0 >= t1) return;

  __shared__ unsigned short Qs[128 * 128];   // 32KB, [row][k] swizzled
  __shared__ unsigned short Ks[64 * 128];    // 16KB
  __shared__ int Morig[128];
  __shared__ int NorigBuf[2][64];            // double-buffered vs append
  __shared__ unsigned runkey[128];
  char* Qsb = (char*)Qs;
  char* Ksb = (char*)Ks;

  int tid = threadIdx.x;
  int lane = tid & 63, wv = tid >> 6;
  int l31 = lane & 31, lhi = lane >> 5;
  int mrow = wv * 32 + l31;                  // this lane's m column (Q row)

  // stage Q tile: 128 rows x 16 chunks of 16B (pure copy, swizzled)
  for (int i = tid; i < 2048; i += 256) {
    int row = i >> 4, ck = i & 15;
    int cm = mt * 128 + row;
    int col = (cm < mc) ? qlist[b * M_ + cm] : qlist[b * M_];
    if (ck == 0) Morig[row] = (cm < mc) ? col : -1;
    uint4 v = *(const uint4*)&qkb[((size_t)b * M_ + col) * DK_ + ck * 8];
    *(uint4*)(Qsb + (row << 8) + ((ck ^ (row & 7)) << 4)) = v;
  }
  if (tid < 128) runkey[tid] = 0u;
  __syncthreads();

  int qswz = (mrow & 7) << 4;
  int kswz = (l31 & 7) << 4;

  for (int tt = t0; tt < t1; ++tt) {
    int nbase = tt << 6;
    int par = tt & 1;
    // stage K tile: 64 rows x 16 chunks
    for (int i = tid; i < 1024; i += 256) {
      int row = i >> 4, ck = i & 15;
      int jn = nbase + row;
      int ncol = (jn < nc) ? nlist[b * N_ + jn] : nlist[b * N_];
      if (ck == 0) NorigBuf[par][row] = (jn < nc) ? ncol : -1;
      uint4 v = *(const uint4*)&mkb[((size_t)b * N_ + ncol) * DK_ + ck * 8];
      *(uint4*)(Ksb + (row << 8) + ((ck ^ (row & 7)) << 4)) = v;
    }
    __syncthreads();

    f32x16 acc0, acc1;
    #pragma unroll
    for (int r = 0; r < 16; ++r) { acc0[r] = 0.0f; acc1[r] = 0.0f; }
    #pragma unroll
    for (int kc = 0; kc < 8; ++kc) {
      int koff = (kc << 5) | (lhi << 4);
      bf16x8 bq = *(const bf16x8*)(Qsb + (mrow << 8) + (koff ^ qswz));
      bf16x8 a0 = *(const bf16x8*)(Ksb + (l31 << 8) + (koff ^ kswz));
      bf16x8 a1 = *(const bf16x8*)(Ksb + ((32 + l31) << 8) + (koff ^ kswz));
      acc0 = __builtin_amdgcn_mfma_f32_32x32x16_bf16(a0, bq, acc0, 0, 0, 0);
      acc1 = __builtin_amdgcn_mfma_f32_32x32x16_bf16(a1, bq, acc1, 0, 0, 0);
    }

    // column max over this lane's 32 scores (col = mrow for every reg)
    float cmx = fmaxf(acc0[0], acc1[0]);
    #pragma unroll
    for (int r = 1; r < 16; ++r) cmx = fmaxf(cmx, fmaxf(acc0[r], acc1[r]));
    cmx = fmaxf(cmx, __shfl_xor(cmx, 32));
    if (lane < 32) {                       // exclusive owner of runkey[mrow]
      unsigned k = fkey(cmx);
      if (k > runkey[mrow]) runkey[mrow] = k;
    }
    __syncthreads();
    // merge with global progress (monotone; threshold only tightens)
    if (tid < 128 && Morig[tid] >= 0) {
      unsigned mine = runkey[tid];
      unsigned old = atomicMax(&maxkey[b * M_ + Morig[tid]], mine);
      if (old > mine) runkey[tid] = old;
    }
    __syncthreads();
    // candidate appends (superset of {s_true >= max_true - TH})
    {
      int mo = Morig[mrow];
      if (mo >= 0) {
        float thr = fdec(runkey[mrow]) - MARGIN_;
        #pragma unroll
        for (int r = 0; r < 16; ++r) {
          if (acc0[r] >= thr) {
            int nl = (r & 3) + ((r >> 2) << 3) + (lhi << 2);
            int no = NorigBuf[par][nl];
            if (no >= 0) {
              unsigned slot = atomicAdd(&bcnt[b * M_ + mo], 1u);
              if (slot < (unsigned)BKT_)
                bucket[(((size_t)(b * M_ + mo)) << 6) + slot] = (unsigned)no;
            }
          }
          if (acc1[r] >= thr) {
            int nl = 32 + (r & 3) + ((r >> 2) << 3) + (lhi << 2);
            int no = NorigBuf[par][nl];
            if (no >= 0) {
              unsigned slot = atomicAdd(&bcnt[b * M_ + mo], 1u);
              if (slot < (unsigned)BKT_)
                bucket[(((size_t)(b * M_ + mo)) << 6) + slot] = (unsigned)no;
            }
          }
        }
      }
    }
    __syncthreads();   // protect NorigBuf[par^1]/Ks restage vs this append
  }
}

__device__ __forceinline__ float dot128(const float* __restrict__ q,
                                        const float* __restrict__ k) {
  float s = 0.f;
  #pragma unroll 8
  for (int i = 0; i < DK_; i += 4) {
    float4 a = *(const float4*)&q[i];
    float4 bb = *(const float4*)&k[i];
    s += a.x * bb.x + a.y * bb.y + a.z * bb.z + a.w * bb.w;
  }
  return s;
}

// ---- PV: one wave per active column; exact fp32 rescore of candidates ----
__global__ __launch_bounds__(256)
void pv_exact(const float* __restrict__ qkeyT, const float* __restrict__ mkeyT,
              const unsigned short* __restrict__ mvalT,
              const int* __restrict__ qlist, const int* __restrict__ qcnt,
              const int* __restrict__ nlist, const int* __restrict__ ncnt,
              const unsigned* __restrict__ bcnt, const unsigned* __restrict__ bucket,
              unsigned short* __restrict__ outT) {
  int b = blockIdx.y;
  int wv = threadIdx.x >> 6, lane = threadIdx.x & 63;
  int c = blockIdx.x * 4 + wv;
  if (c >= qcnt[b]) return;
  int m = qlist[b * M_ + c];
  unsigned cnt = bcnt[b * M_ + m];
  const float* qrow = qkeyT + ((size_t)b * M_ + m) * DK_;
  float acc[8] = {0.f, 0.f, 0.f, 0.f, 0.f, 0.f, 0.f, 0.f};
  float lsum = 0.f;

  if (cnt <= (unsigned)BKT_) {
    int n = -1;
    if (lane < (int)cnt) n = (int)bucket[(((size_t)(b * M_ + m)) << 6) + lane];
    float sv = -3.0e38f;
    if (n >= 0) sv = dot128(qrow, mkeyT + ((size_t)b * N_ + n) * DK_);
    float mx = sv;
    #pragma unroll
    for (int o = 32; o > 0; o >>= 1) mx = fmaxf(mx, __shfl_xor(mx, o));
    float e = (n >= 0 && sv >= mx - TH_) ? expf(sv - mx) : 0.f;
    lsum = e;
    #pragma unroll
    for (int o = 32; o > 0; o >>= 1) lsum += __shfl_xor(lsum, o);
    unsigned long long alive = __ballot(e > 0.f);
    while (alive) {
      int lb = __ffsll((unsigned long long)alive) - 1;
      alive &= alive - 1;
      float w = __shfl(e, lb);
      int nn = __shfl(n, lb);
      u16x8 vvv = *(const u16x8*)(mvalT + ((size_t)b * N_ + nn) * DV_ + lane * 8);
      #pragma unroll
      for (int r = 0; r < 8; ++r) acc[r] += w * bf2f(vvv[r]);
    }
  } else {
    // overflow fallback (statistically unreachable): exact two-pass
    int nc = ncnt[b];
    float mx = -3.0e38f;
    for (int base = 0; base < nc; base += 64) {
      int jn = base + lane;
      float sv = -3.0e38f;
      if (jn < nc) {
        int n = nlist[b * N_ + jn];
        sv = dot128(qrow, mkeyT + ((size_t)b * N_ + n) * DK_);
      }
      mx = fmaxf(mx, sv);
    }
    #pragma unroll
    for (int o = 32; o > 0; o >>= 1) mx = fmaxf(mx, __shfl_xor(mx, o));
    for (int base = 0; base < nc; base += 64) {
      int jn = base + lane;
      int n = -1;
      float sv = -3.0e38f;
      if (jn < nc) {
        n = nlist[b * N_ + jn];
        sv = dot128(qrow, mkeyT + ((size_t)b * N_ + n) * DK_);
      }
      float e = (n >= 0 && sv >= mx - TH_) ? expf(sv - mx) : 0.f;
      lsum += e;
      unsigned long long alive = __ballot(e > 0.f);
      while (alive) {
        int lb = __ffsll((unsigned long long)alive) - 1;
        alive &= alive - 1;
        float w = __shfl(e, lb);
        int nn = __shfl(n, lb);
        u16x8 vvv = *(const u16x8*)(mvalT + ((size_t)b * N_ + nn) * DV_ + lane * 8);
        #pragma unroll
        for (int r = 0; r < 8; ++r) acc[r] += w * bf2f(vvv[r]);
      }
    }
    #pragma unroll
    for (int o = 32; o > 0; o >>= 1) lsum += __shfl_xor(lsum, o);
  }

  float inv = (lsum > 0.f) ? 1.0f / lsum : 0.0f;
  u16x8 ov;
  #pragma unroll
  for (int r = 0; r < 8; ++r) ov[r] = f2bf(acc[r] * inv);
  *(u16x8*)(outT + ((size_t)b * M_ + m) * DV_ + lane * 8) = ov;
}

// ---- transpose outT bf16 [B][M][Dv] -> out fp32 [B][Dv][M], applying qmask ----
__global__ __launch_bounds__(256)
void finalize_T(const unsigned short* __restrict__ outT, const int* __restrict__ qmask,
                float* __restrict__ out) {
  __shared__ float T[64][65];
  int b = blockIdx.z, dvt = blockIdx.y, mt = blockIdx.x;
  int lane = threadIdx.x & 63, ri = threadIdx.x >> 6;
  #pragma unroll
  for (int k = 0; k < 16; ++k) {
    int ml = ri * 16 + k;
    int m = mt * 64 + ml;
    bool act = (qmask[b * M_ + m] != 0);
    T[ml][lane] = act ? bf2f(outT[((size_t)b * M_ + m) * DV_ + dvt * 64 + lane]) : 0.f;
  }
  __syncthreads();
  #pragma unroll
  for (int k = 0; k < 16; ++k) {
    int dvl = ri * 16 + k;
    out[((size_t)b * DV_ + dvt * 64 + dvl) * M_ + mt * 64 + lane] = T[lane][dvl];
  }
}

extern "C" void kernel_launch(void* const* d_in, const int* in_sizes, int n_in,
                              void* d_out, int out_size, void* d_ws, size_t ws_size,
                              hipStream_t stream) {
  const float* qkey  = (const float*)d_in[0];
  const int*   qmask = (const int*)d_in[1];
  const float* mkey  = (const float*)d_in[2];
  const float* mval  = (const float*)d_in[3];
  const int*   mmask = (const int*)d_in[4];
  float* out = (float*)d_out;

  uint8_t* w = (uint8_t*)d_ws;
  unsigned*       maxkey = (unsigned*)(w + 0);              // B*M u32
  unsigned*       bcnt   = (unsigned*)(w + 100352);         // B*M u32
  int*            qcnt   = (int*)(w + 200704);
  int*            ncnt   = (int*)(w + 200736);
  int*            qlist  = (int*)(w + 200832);              // B*M
  int*            nlist  = (int*)(w + 301184);              // B*N
  unsigned*       bucket = (unsigned*)(w + 501888);         // B*M*64   -> 6924416
  float*          qkeyT  = (float*)(w + 6924416);           // B*M*128 f32 (x40)
  float*          mkeyT  = (float*)(w + 19769472);          // B*N*128 f32
  unsigned short* qkb    = (unsigned short*)(w + 45459584); // B*M*128 bf16 (x40)
  unsigned short* mkb    = (unsigned short*)(w + 51882112); // B*N*128 bf16
  unsigned short* outTb  = (unsigned short*)(w + 64727168); // B*M*512 bf16
  unsigned short* mvalT  = (unsigned short*)(w + 90417280); // B*N*512 bf16
  // end: 141,797,504 bytes (< 148 MB proven available)

  hipMemsetAsync(d_ws, 0, 200832, stream);   // maxkey + bcnt + counts

  scan_masks<<<dim3(B_, 2), 256, 0, stream>>>(qmask, mmask, qlist, nlist, qcnt, ncnt);
  transpose_key<<<dim3(M_ / 64, DK_ / 64, B_), 256, 0, stream>>>(qkey, qkeyT, qkb, M_, 40.0f);
  transpose_key<<<dim3(N_ / 64, DK_ / 64, B_), 256, 0, stream>>>(mkey, mkeyT, mkb, N_, 1.0f);
  transpose_val<<<dim3(N_ / 64, DV_ / 64, B_), 256, 0, stream>>>(mval, mvalT);

  score_mfma<<<B_ * MT128_ * NSEG_, 256, 0, stream>>>(
      qkb, mkb, qlist, nlist, qcnt, ncnt, maxkey, bcnt, bucket);

  pv_exact<<<dim3((M_ + 3) / 4, B_), 256, 0, stream>>>(
      qkeyT, mkeyT, mvalT, qlist, qcnt, nlist, ncnt, bcnt, bucket, outTb);

  finalize_T<<<dim3(M_ / 64, DV_ / 64, B_), 256, 0, stream>>>(outTb, qmask, out);
}

// Round 5
// 186.767 us; speedup vs baseline: 5.5917x; 1.1364x over previous
//
#include <hip/hip_runtime.h>
#include <stdint.h>

#define B_    8
#define DK_   128
#define DV_   512
#define M_    3136      // H*W
#define N_    6272      // T*H*W
#define MT128_ 25       // ceil(3136/128)
#define NSEG_ 8
#define NTILES_ 98      // N_/64 dense
#define TH_   30.0f
#define MARGIN_ 36.0f
#define BKT_  64

typedef short bf16x8 __attribute__((ext_vector_type(8)));
typedef float f32x16 __attribute__((ext_vector_type(16)));
typedef unsigned short u16x8 __attribute__((ext_vector_type(8)));

// ---- monotone float<->uint key for atomicMax on floats ----
__device__ __forceinline__ unsigned fkey(float x) {
  unsigned u = __float_as_uint(x);
  return (u & 0x80000000u) ? ~u : (u | 0x80000000u);
}
__device__ __forceinline__ float fdec(unsigned k) {
  return __uint_as_float((k & 0x80000000u) ? (k & 0x7fffffffu) : ~k);
}
__device__ __forceinline__ unsigned short f2bf(float x) {
  unsigned u = __float_as_uint(x);
  return (unsigned short)((u + 0x7fffu + ((u >> 16) & 1u)) >> 16);
}
__device__ __forceinline__ float bf2f(unsigned short h) {
  return __uint_as_float(((unsigned)h) << 16);
}

// ---- fused prep: transposes + q-scan + workspace zeroing, one launch ----
// grid ranges: [0,784) qkey T; [784,2352) mkey T; [2352,8624) mval T;
//              [8624,8632) q scan; [8632,8681) zero maxkey+bcnt
__global__ __launch_bounds__(256)
void prep_kernel(const float* __restrict__ qkey, const int* __restrict__ qmask,
                 const float* __restrict__ mkey, const float* __restrict__ mval,
                 float* __restrict__ qkeyT, unsigned short* __restrict__ qkb,
                 float* __restrict__ mkeyT, unsigned short* __restrict__ mkb,
                 unsigned short* __restrict__ mvalT,
                 int* __restrict__ qlist, int* __restrict__ qcnt,
                 unsigned* __restrict__ zbase) {
  __shared__ float T[64][65];
  int r = blockIdx.x;
  int lane = threadIdx.x & 63, ri = threadIdx.x >> 6;
  if (r < 784) {                       // qkey [B][128][M] -> T fp32+bf16, x40
    int xt = r % 49, dt = (r / 49) & 1, b = r / 98;
    #pragma unroll
    for (int k = 0; k < 16; ++k) {
      int dl = ri * 16 + k;
      T[dl][lane] = qkey[((size_t)b * DK_ + dt * 64 + dl) * M_ + xt * 64 + lane];
    }
    __syncthreads();
    #pragma unroll
    for (int k = 0; k < 16; ++k) {
      int xl = ri * 16 + k;
      float v = 40.0f * T[lane][xl];
      size_t idx = ((size_t)b * M_ + xt * 64 + xl) * DK_ + dt * 64 + lane;
      qkeyT[idx] = v;
      qkb[idx] = f2bf(v);
    }
  } else if (r < 2352) {               // mkey [B][128][N] -> T fp32+bf16
    int r2 = r - 784;
    int xt = r2 % 98, dt = (r2 / 98) & 1, b = r2 / 196;
    #pragma unroll
    for (int k = 0; k < 16; ++k) {
      int dl = ri * 16 + k;
      T[dl][lane] = mkey[((size_t)b * DK_ + dt * 64 + dl) * N_ + xt * 64 + lane];
    }
    __syncthreads();
    #pragma unroll
    for (int k = 0; k < 16; ++k) {
      int xl = ri * 16 + k;
      float v = T[lane][xl];
      size_t idx = ((size_t)b * N_ + xt * 64 + xl) * DK_ + dt * 64 + lane;
      mkeyT[idx] = v;
      mkb[idx] = f2bf(v);
    }
  } else if (r < 8624) {               // mval [B][512][N] -> bf16 [B][N][512]
    int r3 = r - 2352;
    int nt = r3 % 98, dvt = (r3 / 98) & 7, b = r3 / 784;
    #pragma unroll
    for (int k = 0; k < 16; ++k) {
      int dvl = ri * 16 + k;
      T[dvl][lane] = mval[((size_t)b * DV_ + dvt * 64 + dvl) * N_ + nt * 64 + lane];
    }
    __syncthreads();
    #pragma unroll
    for (int k = 0; k < 16; ++k) {
      int nl = ri * 16 + k;
      mvalT[((size_t)b * N_ + nt * 64 + nl) * DV_ + dvt * 64 + lane] = f2bf(T[lane][nl]);
    }
  } else if (r < 8632) {               // q-mask compaction
    int b = r - 8624;
    __shared__ int wsum[4];
    __shared__ int cbase;
    int tid = threadIdx.x, wv = tid >> 6;
    if (tid == 0) cbase = 0;
    __syncthreads();
    for (int base = 0; base < M_; base += 256) {
      int i = base + tid;
      int flag = (i < M_) ? (qmask[b * M_ + i] != 0) : 0;
      unsigned long long bal = __ballot(flag);
      int prefix = __popcll(bal & ((1ull << lane) - 1ull));
      if (lane == 0) wsum[wv] = __popcll(bal);
      __syncthreads();
      int woff = 0;
      for (int t = 0; t < wv; ++t) woff += wsum[t];
      int total = wsum[0] + wsum[1] + wsum[2] + wsum[3];
      if (flag) qlist[b * M_ + cbase + woff + prefix] = i;
      __syncthreads();
      if (tid == 0) cbase += total;
      __syncthreads();
    }
    if (tid == 0) qcnt[b] = cbase;
  } else {                             // zero maxkey+bcnt (49 x 4096B = 200704)
    int z = r - 8632;
    unsigned* p = zbase + z * 1024;
    for (int i = threadIdx.x; i < 1024; i += 256) p[i] = 0u;
  }
}

// ---- bf16-MFMA score: dense n, Q in regs, gload_lds dbuf pipeline ----
__global__ __launch_bounds__(256, 4)
void score_mfma(const unsigned short* __restrict__ qkb, const unsigned short* __restrict__ mkb,
                const int* __restrict__ qlist, const int* __restrict__ qcnt,
                const int* __restrict__ mmask,
                unsigned* __restrict__ maxkey, unsigned* __restrict__ bcnt,
                unsigned* __restrict__ bucket) {
  int bid = blockIdx.x;
  int seg = bid & (NSEG_ - 1);
  int t   = bid >> 3;
  int mt  = t % MT128_;
  int b   = t / MT128_;
  int mc = qcnt[b];
  if (mt * 128 >= mc) return;
  int t0 = (NTILES_ * seg) / NSEG_;
  int t1 = (NTILES_ * (seg + 1)) / NSEG_;

  __shared__ unsigned short Ks[2][64 * 128];  // chunk-major: c*1024B + row*16B

  int tid = threadIdx.x;
  int lane = tid & 63, wv = tid >> 6;
  int l31 = lane & 31, lhi = lane >> 5;
  int mrow = wv * 32 + l31;

  // Q fragments in registers (row exclusive per lane-pair)
  int cm = mt * 128 + mrow;
  int col = (cm < mc) ? qlist[b * M_ + cm] : qlist[b * M_];
  int mo  = (cm < mc) ? col : -1;
  const unsigned short* qrow = qkb + ((size_t)b * M_ + col) * DK_;
  bf16x8 qf[8];
  #pragma unroll
  for (int kc = 0; kc < 8; ++kc)
    qf[kc] = *(const bf16x8*)(qrow + (kc * 2 + lhi) * 8);

  const unsigned short* mkb_b = mkb + (size_t)b * N_ * DK_;
  const int* mm_b = mmask + b * N_;

  // prologue: stage tile t0 into buf 0 (DMA, linear dest = wave base + lane*16)
  {
    int nbase = t0 << 6;
    char* kd = (char*)&Ks[0][0];
    #pragma unroll
    for (int i = 0; i < 4; ++i) {
      int c = wv * 4 + i;
      const unsigned short* src = mkb_b + ((size_t)(nbase + lane)) * DK_ + c * 8;
      __builtin_amdgcn_global_load_lds(
          (const __attribute__((address_space(1))) unsigned*)src,
          (__attribute__((address_space(3))) unsigned*)(kd + c * 1024), 16, 0, 0);
    }
  }
  asm volatile("s_waitcnt vmcnt(0)" ::: "memory");
  __syncthreads();

  float runmax = -3.0e38f;

  for (int tt = t0; tt < t1; ++tt) {
    int cur = (tt - t0) & 1;
    int nbase = tt << 6;
    // issue next-tile stage first (latency hides under MFMA+epilogue)
    if (tt + 1 < t1) {
      int nb2 = (tt + 1) << 6;
      char* kd = (char*)&Ks[cur ^ 1][0];
      #pragma unroll
      for (int i = 0; i < 4; ++i) {
        int c = wv * 4 + i;
        const unsigned short* src = mkb_b + ((size_t)(nb2 + lane)) * DK_ + c * 8;
        __builtin_amdgcn_global_load_lds(
            (const __attribute__((address_space(1))) unsigned*)src,
            (__attribute__((address_space(3))) unsigned*)(kd + c * 1024), 16, 0, 0);
      }
    }
    // active-n bits for this tile (wave-redundant, coalesced)
    unsigned long long bits = __ballot(mm_b[nbase + lane] != 0);

    const char* kb = (const char*)&Ks[cur][0];
    f32x16 acc0, acc1;
    #pragma unroll
    for (int r = 0; r < 16; ++r) { acc0[r] = 0.f; acc1[r] = 0.f; }
    #pragma unroll
    for (int kc = 0; kc < 8; ++kc) {
      int c = kc * 2 + lhi;
      bf16x8 a0 = *(const bf16x8*)(kb + c * 1024 + l31 * 16);
      bf16x8 a1 = *(const bf16x8*)(kb + c * 1024 + (32 + l31) * 16);
      acc0 = __builtin_amdgcn_mfma_f32_32x32x16_bf16(a0, qf[kc], acc0, 0, 0, 0);
      acc1 = __builtin_amdgcn_mfma_f32_32x32x16_bf16(a1, qf[kc], acc1, 0, 0, 0);
    }

    // masked column max (col = mrow for all 32 regs)
    unsigned long long b0 = bits >> (lhi << 2);
    unsigned long long b1 = (bits >> 32) >> (lhi << 2);
    float cmx = -3.0e38f;
    #pragma unroll
    for (int r = 0; r < 16; ++r) {
      const int pos = (r & 3) + ((r >> 2) << 3);
      if ((b0 >> pos) & 1) cmx = fmaxf(cmx, acc0[r]);
      if ((b1 >> pos) & 1) cmx = fmaxf(cmx, acc1[r]);
    }
    cmx = fmaxf(cmx, __shfl_xor(cmx, 32));
    runmax = fmaxf(runmax, cmx);

    // async global merge: send now, import result after appends (monotone)
    unsigned old = 0u;
    if (lhi == 0 && mo >= 0) old = atomicMax(&maxkey[b * M_ + mo], fkey(runmax));

    // candidate appends (superset of {s_true >= max_true - TH})
    if (mo >= 0) {
      float thr = runmax - MARGIN_;
      #pragma unroll
      for (int r = 0; r < 16; ++r) {
        const int pos = (r & 3) + ((r >> 2) << 3);
        if (((b0 >> pos) & 1) && acc0[r] >= thr) {
          unsigned slot = atomicAdd(&bcnt[b * M_ + mo], 1u);
          if (slot < (unsigned)BKT_)
            bucket[(((size_t)(b * M_ + mo)) << 6) + slot] =
                (unsigned)(nbase + pos + (lhi << 2));
        }
        if (((b1 >> pos) & 1) && acc1[r] >= thr) {
          unsigned slot = atomicAdd(&bcnt[b * M_ + mo], 1u);
          if (slot < (unsigned)BKT_)
            bucket[(((size_t)(b * M_ + mo)) << 6) + slot] =
                (unsigned)(nbase + 32 + pos + (lhi << 2));
        }
      }
    }
    if (lhi == 0) runmax = fmaxf(runmax, fdec(old));   // fdec(0)=NaN -> fmax no-op
    runmax = __shfl(runmax, l31);                      // re-sync lane halves

    asm volatile("s_waitcnt vmcnt(0)" ::: "memory");
    __syncthreads();
  }
}

__device__ __forceinline__ float dot128(const float* __restrict__ q,
                                        const float* __restrict__ k) {
  float s = 0.f;
  #pragma unroll 8
  for (int i = 0; i < DK_; i += 4) {
    float4 a = *(const float4*)&q[i];
    float4 bb = *(const float4*)&k[i];
    s += a.x * bb.x + a.y * bb.y + a.z * bb.z + a.w * bb.w;
  }
  return s;
}

// ---- PV: one wave per active column; exact fp32 rescore of candidates ----
__global__ __launch_bounds__(256)
void pv_exact(const float* __restrict__ qkeyT, const float* __restrict__ mkeyT,
              const unsigned short* __restrict__ mvalT,
              const int* __restrict__ qlist, const int* __restrict__ qcnt,
              const int* __restrict__ mmask,
              const unsigned* __restrict__ bcnt, const unsigned* __restrict__ bucket,
              unsigned short* __restrict__ outT) {
  int b = blockIdx.y;
  int wv = threadIdx.x >> 6, lane = threadIdx.x & 63;
  int c = blockIdx.x * 4 + wv;
  if (c >= qcnt[b]) return;
  int m = qlist[b * M_ + c];
  unsigned cnt = bcnt[b * M_ + m];
  const float* qrow = qkeyT + ((size_t)b * M_ + m) * DK_;
  float acc[8] = {0.f, 0.f, 0.f, 0.f, 0.f, 0.f, 0.f, 0.f};
  float lsum = 0.f;

  if (cnt <= (unsigned)BKT_) {
    int n = -1;
    if (lane < (int)cnt) n = (int)bucket[(((size_t)(b * M_ + m)) << 6) + lane];
    float sv = -3.0e38f;
    if (n >= 0) sv = dot128(qrow, mkeyT + ((size_t)b * N_ + n) * DK_);
    float mx = sv;
    #pragma unroll
    for (int o = 32; o > 0; o >>= 1) mx = fmaxf(mx, __shfl_xor(mx, o));
    float e = (n >= 0 && sv >= mx - TH_) ? expf(sv - mx) : 0.f;
    lsum = e;
    #pragma unroll
    for (int o = 32; o > 0; o >>= 1) lsum += __shfl_xor(lsum, o);
    unsigned long long alive = __ballot(e > 0.f);
    while (alive) {
      int lb = __ffsll((unsigned long long)alive) - 1;
      alive &= alive - 1;
      float w = __shfl(e, lb);
      int nn = __shfl(n, lb);
      u16x8 vvv = *(const u16x8*)(mvalT + ((size_t)b * N_ + nn) * DV_ + lane * 8);
      #pragma unroll
      for (int r = 0; r < 8; ++r) acc[r] += w * bf2f(vvv[r]);
    }
  } else {
    // overflow fallback (statistically unreachable): exact dense two-pass
    float mx = -3.0e38f;
    for (int base = 0; base < N_; base += 64) {
      int n = base + lane;
      float sv = -3.0e38f;
      if (mmask[b * N_ + n] != 0)
        sv = dot128(qrow, mkeyT + ((size_t)b * N_ + n) * DK_);
      mx = fmaxf(mx, sv);
    }
    #pragma unroll
    for (int o = 32; o > 0; o >>= 1) mx = fmaxf(mx, __shfl_xor(mx, o));
    for (int base = 0; base < N_; base += 64) {
      int n = base + lane;
      bool act = (mmask[b * N_ + n] != 0);
      float sv = -3.0e38f;
      if (act) sv = dot128(qrow, mkeyT + ((size_t)b * N_ + n) * DK_);
      float e = (act && sv >= mx - TH_) ? expf(sv - mx) : 0.f;
      lsum += e;
      unsigned long long alive = __ballot(e > 0.f);
      while (alive) {
        int lb = __ffsll((unsigned long long)alive) - 1;
        alive &= alive - 1;
        float w = __shfl(e, lb);
        int nn = __shfl(n, lb);
        u16x8 vvv = *(const u16x8*)(mvalT + ((size_t)b * N_ + nn) * DV_ + lane * 8);
        #pragma unroll
        for (int r = 0; r < 8; ++r) acc[r] += w * bf2f(vvv[r]);
      }
    }
    #pragma unroll
    for (int o = 32; o > 0; o >>= 1) lsum += __shfl_xor(lsum, o);
  }

  float inv = (lsum > 0.f) ? 1.0f / lsum : 0.0f;
  u16x8 ov;
  #pragma unroll
  for (int r = 0; r < 8; ++r) ov[r] = f2bf(acc[r] * inv);
  *(u16x8*)(outT + ((size_t)b * M_ + m) * DV_ + lane * 8) = ov;
}

// ---- transpose outT bf16 [B][M][Dv] -> out fp32 [B][Dv][M], applying qmask ----
__global__ __launch_bounds__(256)
void finalize_T(const unsigned short* __restrict__ outT, const int* __restrict__ qmask,
                float* __restrict__ out) {
  __shared__ float T[64][65];
  int b = blockIdx.z, dvt = blockIdx.y, mt = blockIdx.x;
  int lane = threadIdx.x & 63, ri = threadIdx.x >> 6;
  #pragma unroll
  for (int k = 0; k < 16; ++k) {
    int ml = ri * 16 + k;
    int m = mt * 64 + ml;
    bool act = (qmask[b * M_ + m] != 0);
    T[ml][lane] = act ? bf2f(outT[((size_t)b * M_ + m) * DV_ + dvt * 64 + lane]) : 0.f;
  }
  __syncthreads();
  #pragma unroll
  for (int k = 0; k < 16; ++k) {
    int dvl = ri * 16 + k;
    out[((size_t)b * DV_ + dvt * 64 + dvl) * M_ + mt * 64 + lane] = T[lane][dvl];
  }
}

extern "C" void kernel_launch(void* const* d_in, const int* in_sizes, int n_in,
                              void* d_out, int out_size, void* d_ws, size_t ws_size,
                              hipStream_t stream) {
  const float* qkey  = (const float*)d_in[0];
  const int*   qmask = (const int*)d_in[1];
  const float* mkey  = (const float*)d_in[2];
  const float* mval  = (const float*)d_in[3];
  const int*   mmask = (const int*)d_in[4];
  float* out = (float*)d_out;

  uint8_t* w = (uint8_t*)d_ws;
  unsigned*       maxkey = (unsigned*)(w + 0);              // B*M u32
  unsigned*       bcnt   = (unsigned*)(w + 100352);         // B*M u32
  int*            qcnt   = (int*)(w + 200704);
  int*            qlist  = (int*)(w + 200832);              // B*M
  unsigned*       bucket = (unsigned*)(w + 301184);         // B*M*64
  float*          qkeyT  = (float*)(w + 6723712);           // B*M*128 f32 (x40)
  float*          mkeyT  = (float*)(w + 19568768);          // B*N*128 f32
  unsigned short* qkb    = (unsigned short*)(w + 45258880); // B*M*128 bf16 (x40)
  unsigned short* mkb    = (unsigned short*)(w + 51681408); // B*N*128 bf16
  unsigned short* outTb  = (unsigned short*)(w + 64526464); // B*M*512 bf16
  unsigned short* mvalT  = (unsigned short*)(w + 90216576); // B*N*512 bf16
  // end: 141,596,800 bytes (< previously proven-available workspace)

  prep_kernel<<<8681, 256, 0, stream>>>(qkey, qmask, mkey, mval,
                                        qkeyT, qkb, mkeyT, mkb, mvalT,
                                        qlist, qcnt, maxkey /* zbase: maxkey+bcnt */);

  score_mfma<<<B_ * MT128_ * NSEG_, 256, 0, stream>>>(
      qkb, mkb, qlist, qcnt, mmask, maxkey, bcnt, bucket);

  pv_exact<<<dim3(M_ / 4, B_), 256, 0, stream>>>(
      qkeyT, mkeyT, mvalT, qlist, qcnt, mmask, bcnt, bucket, outTb);

  finalize_T<<<dim3(M_ / 64, DV_ / 64, B_), 256, 0, stream>>>(outTb, qmask, out);
}